// Round 1
// 487.280 us; speedup vs baseline: 1.0380x; 1.0380x over previous
//
#include <hip/hip_runtime.h>
#include <hip/hip_fp16.h>

// GCN: 100K nodes, 1.6M edges, 128 -> 128 -> 128 -> 64 (fp32 in/out)
// CSR by dst via bucket partition (4B packed records); degrees/rowptr/dinv
// computed bucket-locally in p2 (no global random atomics anywhere).
// v2: divergence-free gather (wave sweeps 4 nodes sequentially, 4 edge
// groups x 16 feature threads, unroll 2) + aggregate->GEMM fusion so h
// never round-trips HBM. Per layer boundary: fused {gather,relu,bias,
// 16x128 MFMA tile, dinv prescale} in one block.

#define NN 100000
#define NE 1600000
#define TT (NE + NN)              // edges + self loops
#define BSH 9                      // bucket = dst >> 9 (512 nodes/bucket)
#define NBUCK ((NN + 511) / 512)   // 196
#define EPB1 16384                 // edges per partition block
#define NPB1 ((TT + EPB1 - 1) / EPB1)   // 104

typedef _Float16 f16x8 __attribute__((ext_vector_type(8)));
typedef float f32x4 __attribute__((ext_vector_type(4)));

// ---------------- bucket histogram ----------------

__global__ __launch_bounds__(256) void bucket_count(const int* __restrict__ ei,
                                                    int* __restrict__ gbc) {
    __shared__ int hist[NBUCK];
    const int tid = threadIdx.x;
    const int base = blockIdx.x * EPB1;
    for (int b = tid; b < NBUCK; b += 256) hist[b] = 0;
    __syncthreads();
    for (int i = tid; i < EPB1; i += 256) {
        int e = base + i;
        if (e >= TT) break;
        int d = (e < NE) ? ei[NE + e] : (e - NE);
        atomicAdd(&hist[d >> BSH], 1);
    }
    __syncthreads();
    for (int b = tid; b < NBUCK; b += 256)
        if (hist[b]) atomicAdd(&gbc[b], hist[b]);
}

// single tiny block: exclusive scan of 196 bucket counts -> bbase, gcursor

__global__ __launch_bounds__(256) void scan_buckets(const int* __restrict__ gbc,
                                                    int* __restrict__ bbase,
                                                    int* __restrict__ gcursor,
                                                    int* __restrict__ rowptr) {
    __shared__ int s[256];
    const int t = threadIdx.x;
    int v = (t < NBUCK) ? gbc[t] : 0;
    s[t] = v;
    __syncthreads();
    for (int off = 1; off < 256; off <<= 1) {
        int u = (t >= off) ? s[t - off] : 0;
        __syncthreads();
        s[t] += u;
        __syncthreads();
    }
    if (t < NBUCK) {
        int excl = s[t] - v;
        bbase[t] = excl;
        gcursor[t] = excl;
    }
    if (t == 0) { bbase[NBUCK] = TT; rowptr[NN] = TT; }
}

// ---------------- pass 1: partition into 196 dst-buckets ----------------
// record = src | (dst & 511) << 17   (src < 2^17, local dst < 2^9)

__global__ __launch_bounds__(256) void partition_p1(const int* __restrict__ ei,
                                                    int* __restrict__ gcursor,
                                                    int* __restrict__ part) {
    __shared__ int hist[NBUCK];
    const int tid = threadIdx.x;
    const int base = blockIdx.x * EPB1;
    for (int b = tid; b < NBUCK; b += 256) hist[b] = 0;
    __syncthreads();
    for (int i = tid; i < EPB1; i += 256) {
        int e = base + i;
        if (e >= TT) break;
        int d = (e < NE) ? ei[NE + e] : (e - NE);
        atomicAdd(&hist[d >> BSH], 1);
    }
    __syncthreads();
    for (int b = tid; b < NBUCK; b += 256) {
        int cnt = hist[b];
        hist[b] = cnt ? atomicAdd(&gcursor[b], cnt) : 0;
    }
    __syncthreads();
    for (int i = tid; i < EPB1; i += 256) {
        int e = base + i;
        if (e >= TT) break;
        int s, d;
        if (e < NE) { s = ei[e]; d = ei[NE + e]; }
        else        { s = d = e - NE; }
        int pos = atomicAdd(&hist[d >> BSH], 1);
        part[pos] = s | ((d & 511) << 17);
    }
}

// -------- pass 2: bucket-local count + scan + rowptr/dinv + counting sort ----

__global__ __launch_bounds__(256) void partition_p2(const int* __restrict__ part,
                                                    const int* __restrict__ bbase,
                                                    int* __restrict__ rowptr,
                                                    float* __restrict__ dinv,
                                                    int* __restrict__ col) {
    __shared__ int cnt[512];
    __shared__ int scn[512];
    __shared__ int cur[512];
    const int b = blockIdx.x;
    const int v0 = b << BSH;
    const int nv = min(512, NN - v0);
    const int tid = threadIdx.x;
    const int base = bbase[b];
    const int nrec = bbase[b + 1] - base;

    cnt[tid] = 0; cnt[tid + 256] = 0;
    __syncthreads();
    for (int i = tid; i < nrec; i += 256)
        atomicAdd(&cnt[((unsigned)part[base + i]) >> 17], 1);
    __syncthreads();
    scn[tid] = cnt[tid]; scn[tid + 256] = cnt[tid + 256];
    __syncthreads();
    for (int off = 1; off < 512; off <<= 1) {
        int a = (tid >= off) ? scn[tid - off] : 0;
        int c = (tid + 256 >= off) ? scn[tid + 256 - off] : 0;
        __syncthreads();
        scn[tid] += a; scn[tid + 256] += c;
        __syncthreads();
    }
#pragma unroll
    for (int p = 0; p < 2; p++) {
        int j = tid + p * 256;
        if (j < nv) {
            int excl = scn[j] - cnt[j];
            rowptr[v0 + j] = base + excl;
            dinv[v0 + j] = rsqrtf((float)cnt[j]);   // deg >= 1 (self loop)
            cur[j] = base + excl;
        }
    }
    __syncthreads();
    for (int i = tid; i < nrec; i += 256) {
        int r = part[base + i];
        int pos = atomicAdd(&cur[((unsigned)r) >> 17], 1);
        col[pos] = r & 0x1FFFF;
    }
}

// ---------------- W pre-transpose: W[128][F] fp32 -> Wt[F][128] fp16 ----------

__global__ __launch_bounds__(256) void wt_conv_all(const float* __restrict__ W1,
                                                   const float* __restrict__ W2,
                                                   const float* __restrict__ W3,
                                                   _Float16* __restrict__ Wt1,
                                                   _Float16* __restrict__ Wt2,
                                                   _Float16* __restrict__ Wt3) {
    int idx = blockIdx.x * 256 + threadIdx.x;
    if (idx < 16384) {
        Wt1[(idx % 128) * 128 + idx / 128] = (_Float16)W1[idx];
    } else if (idx < 32768) {
        int i = idx - 16384;
        Wt2[(i % 128) * 128 + i / 128] = (_Float16)W2[i];
    } else if (idx < 40960) {
        int i = idx - 32768;
        Wt3[(i % 64) * 128 + i / 64] = (_Float16)W3[i];
    }
}

// ---------------- MFMA GEMM: Yh[N x F](fp16) = dinv[row] * (A[N x 128] @ W) ----
// Only used for layer 1 (A fp32 = x). Frag layouts m89/m91-verified.

template <int F, bool AHALF>
__global__ __launch_bounds__(256) void gemm_mfma(const void* __restrict__ Ap,
                                                 const _Float16* __restrict__ Wt,
                                                 const float* __restrict__ dinv,
                                                 __half* __restrict__ Yh) {
    constexpr int NT = F / 16;
    __shared__ _Float16 Yl[64][136];

    const int tid = threadIdx.x;
    const int wave = tid >> 6;
    const int lane = tid & 63;
    const int m = lane & 15;
    const int q = lane >> 4;
    const int grow0 = blockIdx.x * 64;
    const int row = grow0 + wave * 16 + m;
    const bool rok = row < NN;

    f32x4 acc[NT];
#pragma unroll
    for (int t = 0; t < NT; t++) acc[t] = (f32x4){0.f, 0.f, 0.f, 0.f};

#pragma unroll
    for (int kt = 0; kt < 128; kt += 32) {
        const int k0 = kt + q * 8;
        union { f16x8 v; _Float16 e[8]; } au;
        if (rok) {
            if constexpr (AHALF) {
                au.v = *reinterpret_cast<const f16x8*>(
                    (const __half*)Ap + (size_t)row * 128 + k0);
            } else {
                const float* A = (const float*)Ap;
                float4 x0 = *reinterpret_cast<const float4*>(A + (size_t)row * 128 + k0);
                float4 x1 = *reinterpret_cast<const float4*>(A + (size_t)row * 128 + k0 + 4);
                au.e[0] = (_Float16)x0.x; au.e[1] = (_Float16)x0.y;
                au.e[2] = (_Float16)x0.z; au.e[3] = (_Float16)x0.w;
                au.e[4] = (_Float16)x1.x; au.e[5] = (_Float16)x1.y;
                au.e[6] = (_Float16)x1.z; au.e[7] = (_Float16)x1.w;
            }
        } else {
#pragma unroll
            for (int j = 0; j < 8; j++) au.e[j] = (_Float16)0.f;
        }
#pragma unroll
        for (int t = 0; t < NT; t++) {
            f16x8 bf = *reinterpret_cast<const f16x8*>(Wt + (t * 16 + m) * 128 + k0);
            acc[t] = __builtin_amdgcn_mfma_f32_16x16x32_f16(au.v, bf, acc[t], 0, 0, 0);
        }
    }
#pragma unroll
    for (int r = 0; r < 4; r++) {
        int lrow = wave * 16 + q * 4 + r;
        int gr = grow0 + lrow;
        float s = (gr < NN) ? dinv[gr] : 0.f;
#pragma unroll
        for (int t = 0; t < NT; t++)
            Yl[lrow][t * 16 + m] = (_Float16)(s * acc[t][r]);
    }
    __syncthreads();
    constexpr int CH = F / 8;
    for (int i = tid; i < 64 * CH; i += 256) {
        int lrow = i / CH, c = i % CH;
        int gr = grow0 + lrow;
        if (gr < NN)
            *reinterpret_cast<f16x8*>(Yh + (size_t)gr * F + c * 8) =
                *reinterpret_cast<const f16x8*>(&Yl[lrow][c * 8]);
    }
}

// ---------------- helpers ----------------

__device__ __forceinline__ void acc_add8(float* acc, float4 raw) {
    const __half2* h2 = reinterpret_cast<const __half2*>(&raw);
#pragma unroll
    for (int qq = 0; qq < 4; qq++) {
        float2 fv = __half22float2(h2[qq]);
        acc[2 * qq]     += fv.x;
        acc[2 * qq + 1] += fv.y;
    }
}

__device__ __forceinline__ void acc_add4(float* acc, float2 raw) {
    const __half2* h2 = reinterpret_cast<const __half2*>(&raw);
#pragma unroll
    for (int qq = 0; qq < 2; qq++) {
        float2 fv = __half22float2(h2[qq]);
        acc[2 * qq]     += fv.x;
        acc[2 * qq + 1] += fv.y;
    }
}

// ---------------- fused aggregate + next-layer GEMM ----------------
// Block = 256 thr = 4 waves = 16 nodes. Gather phase: wave sweeps its 4
// nodes SEQUENTIALLY; lane = (edge-group eg 0..3) x (feature chunk f 0..15,
// 8 halves each). No inter-node divergence; only ceil(deg/4) remainder
// waste (~9%). Unroll 2 -> 8 gathers (2KB) in flight per wave.
// h = relu(dinv[v]*sum + bias) staged fp16 in LDS -> 16x128 @ Wt MFMA ->
// D scaled by dinv[row] (prescale for next gather) -> coalesced store.

template <int FOUT>
__global__ __launch_bounds__(256) void fused_agg_gemm(
        const __half* __restrict__ XWh,      // [NN][128] fp16, prescaled
        const int* __restrict__ rowptr,
        const int* __restrict__ col,
        const float* __restrict__ dinv,
        const float* __restrict__ bias,      // [128]
        const _Float16* __restrict__ Wt,     // [FOUT][128] fp16
        __half* __restrict__ Yout) {         // [NN][FOUT] fp16, prescaled
    __shared__ _Float16 Hs[16][136];
    __shared__ _Float16 Ds[16][FOUT + 8];

    const int tid = threadIdx.x;
    const int wave = tid >> 6;
    const int lane = tid & 63;
    const int f = lane & 15;          // feature chunk (8 halves = 16B)
    const int eg = lane >> 4;         // edge group 0..3
    const int v0 = blockIdx.x * 16;
    const float4* base = reinterpret_cast<const float4*>(XWh);

    // ---- gather phase: 4 nodes per wave, sequential ----
#pragma unroll 1
    for (int i = 0; i < 4; i++) {
        const int lrow = wave * 4 + i;
        const int v = v0 + lrow;
        const int beg = rowptr[v];
        const int end = rowptr[v + 1];
        float acc[8] = {0.f, 0.f, 0.f, 0.f, 0.f, 0.f, 0.f, 0.f};
        int e = beg + eg;
        for (; e + 4 < end; e += 8) {
            int u0 = col[e];
            int u1 = col[e + 4];
            float4 r0 = base[(size_t)u0 * 16 + f];
            float4 r1 = base[(size_t)u1 * 16 + f];
            acc_add8(acc, r0);
            acc_add8(acc, r1);
        }
        if (e < end) {
            int u = col[e];
            float4 r = base[(size_t)u * 16 + f];
            acc_add8(acc, r);
        }
        // reduce across the 4 edge groups (lanes f, f+16, f+32, f+48)
#pragma unroll
        for (int qq = 0; qq < 8; qq++) {
            acc[qq] += __shfl_xor(acc[qq], 16);
            acc[qq] += __shfl_xor(acc[qq], 32);
        }
        if (eg == 0) {
            const float dv = dinv[v];
            union { f16x8 v8; _Float16 e8[8]; } hu;
#pragma unroll
            for (int qq = 0; qq < 8; qq++) {
                float r = dv * acc[qq] + bias[f * 8 + qq];
                hu.e8[qq] = (_Float16)fmaxf(r, 0.f);
            }
            *reinterpret_cast<f16x8*>(&Hs[lrow][f * 8]) = hu.v8;
        }
    }
    __syncthreads();

    // ---- GEMM phase: D[16xFOUT] = dinv[row] * (Hs[16x128] @ Wt^T) ----
    constexpr int TPW = FOUT / 64;    // col tiles per wave: 2 (F=128) or 1
    const int m = lane & 15;
    const int q = lane >> 4;
    f32x4 gacc[TPW];
#pragma unroll
    for (int t = 0; t < TPW; t++) gacc[t] = (f32x4){0.f, 0.f, 0.f, 0.f};
#pragma unroll
    for (int kt = 0; kt < 128; kt += 32) {
        const int k0 = kt + q * 8;
        f16x8 av = *reinterpret_cast<const f16x8*>(&Hs[m][k0]);
#pragma unroll
        for (int t = 0; t < TPW; t++) {
            const int gc = (wave * TPW + t) * 16 + m;
            f16x8 bv = *reinterpret_cast<const f16x8*>(Wt + gc * 128 + k0);
            gacc[t] = __builtin_amdgcn_mfma_f32_16x16x32_f16(av, bv, gacc[t], 0, 0, 0);
        }
    }
#pragma unroll
    for (int r = 0; r < 4; r++) {
        const int lrow = q * 4 + r;
        const float s = dinv[v0 + lrow];
#pragma unroll
        for (int t = 0; t < TPW; t++)
            Ds[lrow][(wave * TPW + t) * 16 + m] = (_Float16)(s * gacc[t][r]);
    }
    __syncthreads();
    constexpr int CH = FOUT / 8;
    for (int i2 = tid; i2 < 16 * CH; i2 += 256) {
        int lrow = i2 / CH, c = i2 % CH;
        *reinterpret_cast<f16x8*>(Yout + (size_t)(v0 + lrow) * FOUT + c * 8) =
            *reinterpret_cast<const f16x8*>(&Ds[lrow][c * 8]);
    }
}

// ---------------- final aggregate: F=64, fp32 out, bias, no relu ----------

__global__ __launch_bounds__(256) void agg_final(
        const __half* __restrict__ XWh,      // [NN][64] fp16, prescaled
        const int* __restrict__ rowptr,
        const int* __restrict__ col,
        const float* __restrict__ dinv,
        const float* __restrict__ bias,      // [64]
        float* __restrict__ out) {
    const int tid = threadIdx.x;
    const int wave = tid >> 6;
    const int lane = tid & 63;
    const int f = lane & 15;          // feature chunk (4 halves = 8B)
    const int eg = lane >> 4;         // edge group 0..3
    const int v0 = blockIdx.x * 16;
    const float2* base = reinterpret_cast<const float2*>(XWh);

#pragma unroll 1
    for (int i = 0; i < 4; i++) {
        const int v = v0 + wave * 4 + i;
        const int beg = rowptr[v];
        const int end = rowptr[v + 1];
        float acc[4] = {0.f, 0.f, 0.f, 0.f};
        int e = beg + eg;
        for (; e + 4 < end; e += 8) {
            int u0 = col[e];
            int u1 = col[e + 4];
            float2 r0 = base[(size_t)u0 * 16 + f];
            float2 r1 = base[(size_t)u1 * 16 + f];
            acc_add4(acc, r0);
            acc_add4(acc, r1);
        }
        if (e < end) {
            int u = col[e];
            float2 r = base[(size_t)u * 16 + f];
            acc_add4(acc, r);
        }
#pragma unroll
        for (int qq = 0; qq < 4; qq++) {
            acc[qq] += __shfl_xor(acc[qq], 16);
            acc[qq] += __shfl_xor(acc[qq], 32);
        }
        if (eg == 0) {
            const float dv = dinv[v];
            float4 w;
            w.x = dv * acc[0] + bias[f * 4 + 0];
            w.y = dv * acc[1] + bias[f * 4 + 1];
            w.z = dv * acc[2] + bias[f * 4 + 2];
            w.w = dv * acc[3] + bias[f * 4 + 3];
            *reinterpret_cast<float4*>(out + (size_t)v * 64 + f * 4) = w;
        }
    }
}

// ---------------- launch ----------------

extern "C" void kernel_launch(void* const* d_in, const int* in_sizes, int n_in,
                              void* d_out, int out_size, void* d_ws, size_t ws_size,
                              hipStream_t stream) {
    const float* x  = (const float*)d_in[0];
    const int*   ei = (const int*)d_in[1];
    const float* W1 = (const float*)d_in[2];
    const float* b1 = (const float*)d_in[3];
    const float* W2 = (const float*)d_in[4];
    const float* b2 = (const float*)d_in[5];
    const float* W3 = (const float*)d_in[6];
    const float* b3 = (const float*)d_in[7];
    float* out = (float*)d_out;

    char* p = (char*)d_ws;
    int*      rowptr  = (int*)p;       p += 400016;
    float*    dinv    = (float*)p;     p += 400000;
    int*      gbc     = (int*)p;       p += 1024;
    int*      bbase   = (int*)p;       p += 1024;
    int*      gcursor = (int*)p;       p += 1024;
    _Float16* Wt1     = (_Float16*)p;  p += 32768;
    _Float16* Wt2     = (_Float16*)p;  p += 32768;
    _Float16* Wt3     = (_Float16*)p;  p += 16384;
    int*      part    = (int*)p;       p += (size_t)TT * 4;       // 6.8 MB
    int*      col     = (int*)p;       p += (size_t)TT * 4;       // 6.8 MB
    __half*   xwh1    = (__half*)p;    p += (size_t)NN * 128 * 2; // 25.6 MB
    __half*   xwh2    = (__half*)p;                                // 25.6 MB
    __half*   xwh3    = xwh1;          // layer-3 input reuses xwh1's space

    hipMemsetAsync(gbc, 0, NBUCK * 4, stream);
    wt_conv_all<<<160, 256, 0, stream>>>(W1, W2, W3, Wt1, Wt2, Wt3);
    bucket_count<<<NPB1, 256, 0, stream>>>(ei, gbc);
    scan_buckets<<<1, 256, 0, stream>>>(gbc, bbase, gcursor, rowptr);
    partition_p1<<<NPB1, 256, 0, stream>>>(ei, gcursor, part);
    partition_p2<<<NBUCK, 256, 0, stream>>>(part, bbase, rowptr, dinv, col);

    const int gb = (NN + 63) / 64;   // 1563
    const int fb = NN / 16;          // 6250 (exact)
    // layer 1 GEMM (A fp32): xwh1 = dinv * (x @ W1)
    gemm_mfma<128, false><<<gb, 256, 0, stream>>>(x, Wt1, dinv, xwh1);
    // fused: h1 = relu(dinv*agg(xwh1)+b1); xwh2 = dinv * (h1 @ W2)
    fused_agg_gemm<128><<<fb, 256, 0, stream>>>(xwh1, rowptr, col, dinv, b1,
                                                Wt2, xwh2);
    // fused: h2 = relu(dinv*agg(xwh2)+b2); xwh3 = dinv * (h2 @ W3)
    fused_agg_gemm<64><<<fb, 256, 0, stream>>>(xwh2, rowptr, col, dinv, b2,
                                               Wt3, xwh3);
    // final: out = dinv*agg(xwh3) + b3
    agg_final<<<fb, 256, 0, stream>>>(xwh3, rowptr, col, dinv, b3, out);
}

// Round 2
// 455.767 us; speedup vs baseline: 1.1098x; 1.0691x over previous
//
#include <hip/hip_runtime.h>
#include <hip/hip_fp16.h>

// GCN: 100K nodes, 1.6M edges, 128 -> 128 -> 128 -> 64 (fp32 in/out)
// CSR by dst via bucket partition (4B packed records); degrees/rowptr/dinv
// computed bucket-locally in p2 (no global random atomics anywhere).
// v3: aggregate->GEMM fusion kept (h never round-trips HBM), but gather
// reverted to the round-0 proven pattern: thread = (node, f-chunk),
// serial edge loop with unroll 4 (4 independent 16B gathers in flight
// per thread, no shuffles). v2's sequential-node sweep killed MLP
// (3.67 -> 2.96 TB/s) and its shfl reductions caused 500K LDS conflicts.

#define NN 100000
#define NE 1600000
#define TT (NE + NN)              // edges + self loops
#define BSH 9                      // bucket = dst >> 9 (512 nodes/bucket)
#define NBUCK ((NN + 511) / 512)   // 196
#define EPB1 16384                 // edges per partition block
#define NPB1 ((TT + EPB1 - 1) / EPB1)   // 104

typedef _Float16 f16x8 __attribute__((ext_vector_type(8)));
typedef float f32x4 __attribute__((ext_vector_type(4)));

// ---------------- bucket histogram ----------------

__global__ __launch_bounds__(256) void bucket_count(const int* __restrict__ ei,
                                                    int* __restrict__ gbc) {
    __shared__ int hist[NBUCK];
    const int tid = threadIdx.x;
    const int base = blockIdx.x * EPB1;
    for (int b = tid; b < NBUCK; b += 256) hist[b] = 0;
    __syncthreads();
    for (int i = tid; i < EPB1; i += 256) {
        int e = base + i;
        if (e >= TT) break;
        int d = (e < NE) ? ei[NE + e] : (e - NE);
        atomicAdd(&hist[d >> BSH], 1);
    }
    __syncthreads();
    for (int b = tid; b < NBUCK; b += 256)
        if (hist[b]) atomicAdd(&gbc[b], hist[b]);
}

// single tiny block: exclusive scan of 196 bucket counts -> bbase, gcursor

__global__ __launch_bounds__(256) void scan_buckets(const int* __restrict__ gbc,
                                                    int* __restrict__ bbase,
                                                    int* __restrict__ gcursor,
                                                    int* __restrict__ rowptr) {
    __shared__ int s[256];
    const int t = threadIdx.x;
    int v = (t < NBUCK) ? gbc[t] : 0;
    s[t] = v;
    __syncthreads();
    for (int off = 1; off < 256; off <<= 1) {
        int u = (t >= off) ? s[t - off] : 0;
        __syncthreads();
        s[t] += u;
        __syncthreads();
    }
    if (t < NBUCK) {
        int excl = s[t] - v;
        bbase[t] = excl;
        gcursor[t] = excl;
    }
    if (t == 0) { bbase[NBUCK] = TT; rowptr[NN] = TT; }
}

// ---------------- pass 1: partition into 196 dst-buckets ----------------
// record = src | (dst & 511) << 17   (src < 2^17, local dst < 2^9)

__global__ __launch_bounds__(256) void partition_p1(const int* __restrict__ ei,
                                                    int* __restrict__ gcursor,
                                                    int* __restrict__ part) {
    __shared__ int hist[NBUCK];
    const int tid = threadIdx.x;
    const int base = blockIdx.x * EPB1;
    for (int b = tid; b < NBUCK; b += 256) hist[b] = 0;
    __syncthreads();
    for (int i = tid; i < EPB1; i += 256) {
        int e = base + i;
        if (e >= TT) break;
        int d = (e < NE) ? ei[NE + e] : (e - NE);
        atomicAdd(&hist[d >> BSH], 1);
    }
    __syncthreads();
    for (int b = tid; b < NBUCK; b += 256) {
        int cnt = hist[b];
        hist[b] = cnt ? atomicAdd(&gcursor[b], cnt) : 0;
    }
    __syncthreads();
    for (int i = tid; i < EPB1; i += 256) {
        int e = base + i;
        if (e >= TT) break;
        int s, d;
        if (e < NE) { s = ei[e]; d = ei[NE + e]; }
        else        { s = d = e - NE; }
        int pos = atomicAdd(&hist[d >> BSH], 1);
        part[pos] = s | ((d & 511) << 17);
    }
}

// -------- pass 2: bucket-local count + scan + rowptr/dinv + counting sort ----

__global__ __launch_bounds__(256) void partition_p2(const int* __restrict__ part,
                                                    const int* __restrict__ bbase,
                                                    int* __restrict__ rowptr,
                                                    float* __restrict__ dinv,
                                                    int* __restrict__ col) {
    __shared__ int cnt[512];
    __shared__ int scn[512];
    __shared__ int cur[512];
    const int b = blockIdx.x;
    const int v0 = b << BSH;
    const int nv = min(512, NN - v0);
    const int tid = threadIdx.x;
    const int base = bbase[b];
    const int nrec = bbase[b + 1] - base;

    cnt[tid] = 0; cnt[tid + 256] = 0;
    __syncthreads();
    for (int i = tid; i < nrec; i += 256)
        atomicAdd(&cnt[((unsigned)part[base + i]) >> 17], 1);
    __syncthreads();
    scn[tid] = cnt[tid]; scn[tid + 256] = cnt[tid + 256];
    __syncthreads();
    for (int off = 1; off < 512; off <<= 1) {
        int a = (tid >= off) ? scn[tid - off] : 0;
        int c = (tid + 256 >= off) ? scn[tid + 256 - off] : 0;
        __syncthreads();
        scn[tid] += a; scn[tid + 256] += c;
        __syncthreads();
    }
#pragma unroll
    for (int p = 0; p < 2; p++) {
        int j = tid + p * 256;
        if (j < nv) {
            int excl = scn[j] - cnt[j];
            rowptr[v0 + j] = base + excl;
            dinv[v0 + j] = rsqrtf((float)cnt[j]);   // deg >= 1 (self loop)
            cur[j] = base + excl;
        }
    }
    __syncthreads();
    for (int i = tid; i < nrec; i += 256) {
        int r = part[base + i];
        int pos = atomicAdd(&cur[((unsigned)r) >> 17], 1);
        col[pos] = r & 0x1FFFF;
    }
}

// ---------------- W pre-transpose: W[128][F] fp32 -> Wt[F][128] fp16 ----------

__global__ __launch_bounds__(256) void wt_conv_all(const float* __restrict__ W1,
                                                   const float* __restrict__ W2,
                                                   const float* __restrict__ W3,
                                                   _Float16* __restrict__ Wt1,
                                                   _Float16* __restrict__ Wt2,
                                                   _Float16* __restrict__ Wt3) {
    int idx = blockIdx.x * 256 + threadIdx.x;
    if (idx < 16384) {
        Wt1[(idx % 128) * 128 + idx / 128] = (_Float16)W1[idx];
    } else if (idx < 32768) {
        int i = idx - 16384;
        Wt2[(i % 128) * 128 + i / 128] = (_Float16)W2[i];
    } else if (idx < 40960) {
        int i = idx - 32768;
        Wt3[(i % 64) * 128 + i / 64] = (_Float16)W3[i];
    }
}

// ---------------- MFMA GEMM: Yh[N x F](fp16) = dinv[row] * (A[N x 128] @ W) ----
// Only used for layer 1 (A fp32 = x). Frag layouts m89/m91-verified.

template <int F, bool AHALF>
__global__ __launch_bounds__(256) void gemm_mfma(const void* __restrict__ Ap,
                                                 const _Float16* __restrict__ Wt,
                                                 const float* __restrict__ dinv,
                                                 __half* __restrict__ Yh) {
    constexpr int NT = F / 16;
    __shared__ _Float16 Yl[64][136];

    const int tid = threadIdx.x;
    const int wave = tid >> 6;
    const int lane = tid & 63;
    const int m = lane & 15;
    const int q = lane >> 4;
    const int grow0 = blockIdx.x * 64;
    const int row = grow0 + wave * 16 + m;
    const bool rok = row < NN;

    f32x4 acc[NT];
#pragma unroll
    for (int t = 0; t < NT; t++) acc[t] = (f32x4){0.f, 0.f, 0.f, 0.f};

#pragma unroll
    for (int kt = 0; kt < 128; kt += 32) {
        const int k0 = kt + q * 8;
        union { f16x8 v; _Float16 e[8]; } au;
        if (rok) {
            if constexpr (AHALF) {
                au.v = *reinterpret_cast<const f16x8*>(
                    (const __half*)Ap + (size_t)row * 128 + k0);
            } else {
                const float* A = (const float*)Ap;
                float4 x0 = *reinterpret_cast<const float4*>(A + (size_t)row * 128 + k0);
                float4 x1 = *reinterpret_cast<const float4*>(A + (size_t)row * 128 + k0 + 4);
                au.e[0] = (_Float16)x0.x; au.e[1] = (_Float16)x0.y;
                au.e[2] = (_Float16)x0.z; au.e[3] = (_Float16)x0.w;
                au.e[4] = (_Float16)x1.x; au.e[5] = (_Float16)x1.y;
                au.e[6] = (_Float16)x1.z; au.e[7] = (_Float16)x1.w;
            }
        } else {
#pragma unroll
            for (int j = 0; j < 8; j++) au.e[j] = (_Float16)0.f;
        }
#pragma unroll
        for (int t = 0; t < NT; t++) {
            f16x8 bf = *reinterpret_cast<const f16x8*>(Wt + (t * 16 + m) * 128 + k0);
            acc[t] = __builtin_amdgcn_mfma_f32_16x16x32_f16(au.v, bf, acc[t], 0, 0, 0);
        }
    }
#pragma unroll
    for (int r = 0; r < 4; r++) {
        int lrow = wave * 16 + q * 4 + r;
        int gr = grow0 + lrow;
        float s = (gr < NN) ? dinv[gr] : 0.f;
#pragma unroll
        for (int t = 0; t < NT; t++)
            Yl[lrow][t * 16 + m] = (_Float16)(s * acc[t][r]);
    }
    __syncthreads();
    constexpr int CH = F / 8;
    for (int i = tid; i < 64 * CH; i += 256) {
        int lrow = i / CH, c = i % CH;
        int gr = grow0 + lrow;
        if (gr < NN)
            *reinterpret_cast<f16x8*>(Yh + (size_t)gr * F + c * 8) =
                *reinterpret_cast<const f16x8*>(&Yl[lrow][c * 8]);
    }
}

// ---------------- helper ----------------

__device__ __forceinline__ void acc_add8(float* acc, float4 raw) {
    const __half2* h2 = reinterpret_cast<const __half2*>(&raw);
#pragma unroll
    for (int qq = 0; qq < 4; qq++) {
        float2 fv = __half22float2(h2[qq]);
        acc[2 * qq]     += fv.x;
        acc[2 * qq + 1] += fv.y;
    }
}

// ---------------- fused aggregate + next-layer GEMM ----------------
// Block = 256 thr = 16 nodes. Gather phase = round-0 aggregate layout:
// thread = (node tid/16, f-chunk tid%16), serial edge loop unroll 4 ->
// 4 independent 16B gathers in flight per thread, no shuffles. Result
// h = relu(dinv[v]*sum + bias) written f16x8 to LDS. GEMM phase:
// 16x128 @ Wt (16x16x32 MFMA), D scaled by dinv[row] (prescale for the
// next gather), coalesced f16x8 store.

template <int FOUT>
__global__ __launch_bounds__(256) void fused_agg_gemm(
        const __half* __restrict__ XWh,      // [NN][128] fp16, prescaled
        const int* __restrict__ rowptr,
        const int* __restrict__ col,
        const float* __restrict__ dinv,
        const float* __restrict__ bias,      // [128]
        const _Float16* __restrict__ Wt,     // [FOUT][128] fp16
        __half* __restrict__ Yout) {         // [NN][FOUT] fp16, prescaled
    __shared__ _Float16 Hs[16][136];
    __shared__ _Float16 Ds[16][FOUT + 8];

    const int tid = threadIdx.x;
    const int v0 = blockIdx.x * 16;

    // ---- gather phase (round-0 pattern) ----
    {
        const int lnode = tid >> 4;       // 0..15
        const int f = tid & 15;           // 16B chunk
        const int v = v0 + lnode;
        const int beg = rowptr[v];
        const int end = rowptr[v + 1];
        const float4* base = reinterpret_cast<const float4*>(XWh);
        float acc[8] = {0.f, 0.f, 0.f, 0.f, 0.f, 0.f, 0.f, 0.f};
#pragma unroll 4
        for (int e = beg; e < end; e++) {
            int u = col[e];
            float4 raw = base[(size_t)u * 16 + f];
            acc_add8(acc, raw);
        }
        const float dv = dinv[v];
        union { f16x8 v8; _Float16 e8[8]; } hu;
#pragma unroll
        for (int qq = 0; qq < 8; qq++) {
            float r = dv * acc[qq] + bias[f * 8 + qq];
            hu.e8[qq] = (_Float16)fmaxf(r, 0.f);
        }
        *reinterpret_cast<f16x8*>(&Hs[lnode][f * 8]) = hu.v8;
    }
    __syncthreads();

    // ---- GEMM phase: D[16xFOUT] = dinv[row] * (Hs[16x128] @ Wt^T) ----
    constexpr int TPW = FOUT / 64;    // col tiles per wave: 2 (F=128) or 1
    const int wave = tid >> 6;
    const int lane = tid & 63;
    const int m = lane & 15;
    const int q = lane >> 4;
    f32x4 gacc[TPW];
#pragma unroll
    for (int t = 0; t < TPW; t++) gacc[t] = (f32x4){0.f, 0.f, 0.f, 0.f};
#pragma unroll
    for (int kt = 0; kt < 128; kt += 32) {
        const int k0 = kt + q * 8;
        f16x8 av = *reinterpret_cast<const f16x8*>(&Hs[m][k0]);
#pragma unroll
        for (int t = 0; t < TPW; t++) {
            const int gc = (wave * TPW + t) * 16 + m;
            f16x8 bv = *reinterpret_cast<const f16x8*>(Wt + gc * 128 + k0);
            gacc[t] = __builtin_amdgcn_mfma_f32_16x16x32_f16(av, bv, gacc[t], 0, 0, 0);
        }
    }
#pragma unroll
    for (int r = 0; r < 4; r++) {
        const int lrow = q * 4 + r;
        const float s = dinv[v0 + lrow];
#pragma unroll
        for (int t = 0; t < TPW; t++)
            Ds[lrow][(wave * TPW + t) * 16 + m] = (_Float16)(s * gacc[t][r]);
    }
    __syncthreads();
    constexpr int CH = FOUT / 8;
    for (int i2 = tid; i2 < 16 * CH; i2 += 256) {
        int lrow = i2 / CH, c = i2 % CH;
        *reinterpret_cast<f16x8*>(Yout + (size_t)(v0 + lrow) * FOUT + c * 8) =
            *reinterpret_cast<const f16x8*>(&Ds[lrow][c * 8]);
    }
}

// -------- final aggregate: F=64, fp32 out, bias, no relu (round-0 kernel) ----

__global__ __launch_bounds__(256) void agg_final(
        const __half* __restrict__ XWh,      // [NN][64] fp16, prescaled
        const int* __restrict__ rowptr,
        const int* __restrict__ col,
        const float* __restrict__ dinv,
        const float* __restrict__ bias,      // [64]
        float* __restrict__ out) {
    constexpr int TPN = 8;            // 64/8 chunks of 16B
    constexpr int NPB = 256 / TPN;    // 32 nodes/block
    const int v = blockIdx.x * NPB + threadIdx.x / TPN;
    const int f = threadIdx.x % TPN;
    const int beg = rowptr[v];
    const int end = rowptr[v + 1];
    const float4* base = reinterpret_cast<const float4*>(XWh);
    float acc[8] = {0.f, 0.f, 0.f, 0.f, 0.f, 0.f, 0.f, 0.f};
#pragma unroll 4
    for (int e = beg; e < end; e++) {
        int u = col[e];
        float4 raw = base[(size_t)u * TPN + f];
        acc_add8(acc, raw);
    }
    const float dv = dinv[v];
    float r[8];
#pragma unroll
    for (int q = 0; q < 8; q++)
        r[q] = dv * acc[q] + bias[f * 8 + q];
    float* op = out + (size_t)v * 64 + f * 8;
    *reinterpret_cast<float4*>(op)     = make_float4(r[0], r[1], r[2], r[3]);
    *reinterpret_cast<float4*>(op + 4) = make_float4(r[4], r[5], r[6], r[7]);
}

// ---------------- launch ----------------

extern "C" void kernel_launch(void* const* d_in, const int* in_sizes, int n_in,
                              void* d_out, int out_size, void* d_ws, size_t ws_size,
                              hipStream_t stream) {
    const float* x  = (const float*)d_in[0];
    const int*   ei = (const int*)d_in[1];
    const float* W1 = (const float*)d_in[2];
    const float* b1 = (const float*)d_in[3];
    const float* W2 = (const float*)d_in[4];
    const float* b2 = (const float*)d_in[5];
    const float* W3 = (const float*)d_in[6];
    const float* b3 = (const float*)d_in[7];
    float* out = (float*)d_out;

    char* p = (char*)d_ws;
    int*      rowptr  = (int*)p;       p += 400016;
    float*    dinv    = (float*)p;     p += 400000;
    int*      gbc     = (int*)p;       p += 1024;
    int*      bbase   = (int*)p;       p += 1024;
    int*      gcursor = (int*)p;       p += 1024;
    _Float16* Wt1     = (_Float16*)p;  p += 32768;
    _Float16* Wt2     = (_Float16*)p;  p += 32768;
    _Float16* Wt3     = (_Float16*)p;  p += 16384;
    int*      part    = (int*)p;       p += (size_t)TT * 4;       // 6.8 MB
    int*      col     = (int*)p;       p += (size_t)TT * 4;       // 6.8 MB
    __half*   xwh1    = (__half*)p;    p += (size_t)NN * 128 * 2; // 25.6 MB
    __half*   xwh2    = (__half*)p;                                // 25.6 MB
    __half*   xwh3    = xwh1;          // layer-3 input reuses xwh1's space

    hipMemsetAsync(gbc, 0, NBUCK * 4, stream);
    wt_conv_all<<<160, 256, 0, stream>>>(W1, W2, W3, Wt1, Wt2, Wt3);
    bucket_count<<<NPB1, 256, 0, stream>>>(ei, gbc);
    scan_buckets<<<1, 256, 0, stream>>>(gbc, bbase, gcursor, rowptr);
    partition_p1<<<NPB1, 256, 0, stream>>>(ei, gcursor, part);
    partition_p2<<<NBUCK, 256, 0, stream>>>(part, bbase, rowptr, dinv, col);

    const int gb = (NN + 63) / 64;   // 1563
    const int fb = NN / 16;          // 6250 (exact)
    // layer 1 GEMM (A fp32): xwh1 = dinv * (x @ W1)
    gemm_mfma<128, false><<<gb, 256, 0, stream>>>(x, Wt1, dinv, xwh1);
    // fused: h1 = relu(dinv*agg(xwh1)+b1); xwh2 = dinv * (h1 @ W2)
    fused_agg_gemm<128><<<fb, 256, 0, stream>>>(xwh1, rowptr, col, dinv, b1,
                                                Wt2, xwh2);
    // fused: h2 = relu(dinv*agg(xwh2)+b2); xwh3 = dinv * (h2 @ W3)
    fused_agg_gemm<64><<<fb, 256, 0, stream>>>(xwh2, rowptr, col, dinv, b2,
                                               Wt3, xwh3);
    // final: out = dinv*agg(xwh3) + b3
    agg_final<<<NN / 32, 256, 0, stream>>>(xwh3, rowptr, col, dinv, b3, out);
}